// Round 9
// baseline (13880.017 us; speedup 1.0000x reference)
//
#include <hip/hip_runtime.h>
#include <hip/hip_bf16.h>

typedef _Float16 f16;
typedef _Float16 f16x8 __attribute__((ext_vector_type(8)));
typedef float f32x4 __attribute__((ext_vector_type(4)));

#define SN 2048
#define IN_ 128
#define TCH 16       // time chunk: iters/block = TCH + WUP = 112
#define WUP 96
#define RR 64        // rows per block (4 MFMA m-tiles)
#define HPAD 264
#define XPAD 136

#define WB0_SZ (384 * 1024)
#define WB1_SZ (512 * 1024)
#define WBO_SZ (256 * 128)
#define BIAS_OFF_B ((WB0_SZ + WB1_SZ + WBO_SZ) * 2)

struct PrepArgs {
  const float* W[8];   // ff1_0, ff2_0, ta_0, tb_0, ff1_1, ff2_1, ta_1, tb_1
  const float* b[8];
  const float* Wout;
  const float* bout;
};

// Pack f32 weights into per-(frag,lane) f16x8 groups.
// k-map (identical for A and B fragments -> permutation-safe):
//   element e of lane l in k-tile kt covers k = kt*32 + (l>>4)*8 + e
//   col n = nt*16 + (l&15)
__global__ void prep_kernel(PrepArgs p, f16* wbase, float* bbase) {
  int g = blockIdx.x * blockDim.x + threadIdx.x;
  const int NF0 = 12 * 64;
  const int NF1 = 16 * 64;
  const int NFO = 8 * 8;
  const int E0 = NF0 * 64, E1 = E0 + NF1 * 64, E2 = E1 + NFO * 64;
  if (g < E0) {
    int f = g >> 6, lane = g & 63;
    int kt = f >> 6, nt = f & 63;
    int k = kt * 32 + ((lane >> 4) << 3);
    int n = nt * 16 + (lane & 15);
    const float* W = p.W[n >> 8];    // layer0 weight [384][256]
    int j = n & 255;
    f16x8 v;
#pragma unroll
    for (int e = 0; e < 8; ++e) v[e] = (f16)W[(k + e) * 256 + j];
    *(f16x8*)(wbase + (size_t)g * 8) = v;
  } else if (g < E1) {
    int g1 = g - E0;
    int f = g1 >> 6, lane = g1 & 63;
    int kt = f >> 6, nt = f & 63;
    int k = kt * 32 + ((lane >> 4) << 3);
    int n = nt * 16 + (lane & 15);
    const float* W = p.W[4 + (n >> 8)];  // layer1 weight [512][256]
    int j = n & 255;
    f16x8 v;
#pragma unroll
    for (int e = 0; e < 8; ++e) v[e] = (f16)W[(k + e) * 256 + j];
    *(f16x8*)(wbase + (size_t)WB0_SZ + (size_t)g1 * 8) = v;
  } else if (g < E2) {
    int g2 = g - E1;
    int f = g2 >> 6, lane = g2 & 63;
    int kt = f >> 3, nt = f & 7;
    int k = kt * 32 + ((lane >> 4) << 3);
    int n = nt * 16 + (lane & 15);
    f16x8 v;
#pragma unroll
    for (int e = 0; e < 8; ++e) v[e] = (f16)p.Wout[(k + e) * 128 + n];
    *(f16x8*)(wbase + (size_t)(WB0_SZ + WB1_SZ) + (size_t)g2 * 8) = v;
  } else {
    int g3 = g - E2;
    if (g3 < 1024) {
      bbase[g3] = p.b[g3 >> 8][g3 & 255];
    } else if (g3 < 2048) {
      int q = g3 - 1024;
      bbase[1024 + q] = p.b[4 + (q >> 8)][q & 255];
    } else if (g3 < 2176) {
      bbase[2048 + (g3 - 2048)] = p.bout[g3 - 2048];
    }
  }
}

__device__ __forceinline__ float fast_tanh(float v) {
  float e = __expf(2.f * v);
  return 1.f - 2.f / (e + 1.f);
}
__device__ __forceinline__ float fast_sigmoid(float v) {
  return 1.f / (1.f + __expf(-v));
}

#define MFMA16(a, b, c) __builtin_amdgcn_mfma_f32_16x16x32_f16((a), (b), (c), 0, 0, 0)

// 256 blocks = 128 time-chunks (TCH=16, WUP=96 -> 112 iters) x 2 row-groups
// of 64 rows. Rationale (R0-R8 evidence): per-block-iter time is pinned at
// ~93us by a ~20 GB/s per-CU weight-ingestion cap (1.79 MB weights/CU-iter),
// insensitive to delivery mechanism / barriers / aggregate BW. So: (1) cut
// iterations 128->112 via TCH=16; (2) 256 blocks -> 32 CUs/XCD share the
// weight stream, which measured 26% L2-miss (R7) vs 53% at 16 CUs/XCD (R8)
// -> lower avg latency -> higher per-CU rate. RR=64: each fragment feeds 4
// m-tile MFMAs. 8 waves/block, 2/SIMD. Wave w owns gate n-frags {g*16+2w+s};
// all four gates of a (row,col) sit in the same lane -> elementwise in regs.
__global__ __launch_bounds__(512, 2)
void scan_kernel(const float* __restrict__ x, const float* __restrict__ dtp,
                 const f16* __restrict__ wb0, const f16* __restrict__ wb1,
                 const f16* __restrict__ wbO, const float* __restrict__ bb,
                 float* __restrict__ out) {   // *** d_out is FLOAT32 ***
  __shared__ __align__(16) f16 xA[RR][XPAD];       // 17.4 KB
  __shared__ __align__(16) f16 h0s[2][RR][HPAD];   // 67.6 KB
  __shared__ __align__(16) f16 h1s[2][RR][HPAD];   // 67.6 KB
  __shared__ float dts[2][RR];

  const int tid = threadIdx.x;
  const int lane = tid & 63;
  const int w = tid >> 6;                 // 0..7
  const int c = blockIdx.x >> 1;          // time chunk 0..127
  const int r0 = (blockIdx.x & 1) * RR;   // batch-row base (0 or 64)

  const int mrow = lane & 15;
  const int kgrp = (lane >> 4) * 8;
  const int rbase = (lane >> 4) * 4;

  for (int i = tid; i < 2 * RR * HPAD; i += 512) {
    (&h0s[0][0][0])[i] = (f16)0.f;
    (&h1s[0][0][0])[i] = (f16)0.f;
  }

  // biases in registers
  float b0r[8], b1r[8];
#pragma unroll
  for (int g = 0; g < 4; ++g)
#pragma unroll
    for (int s = 0; s < 2; ++s) {
      b0r[g * 2 + s] = bb[(g * 16 + 2 * w + s) * 16 + mrow];
      b1r[g * 2 + s] = bb[1024 + (g * 16 + 2 * w + s) * 16 + mrow];
    }
  const float bOr = bb[2048 + w * 16 + mrow];

  int tb = c * TCH - WUP;
  if (tb < 0) tb = 0;
  const int te = (c + 1) * TCH;
  const int tw = c * TCH;

  // weight frag pointers: frag (kt, nt) at (kt*64 + nt)*64 + lane (f16x8 units)
  const f16x8* wp0 = (const f16x8*)wb0 + (size_t)(2 * w) * 64 + lane;
  const f16x8* wp1 = (const f16x8*)wb1 + (size_t)(2 * w) * 64 + lane;
  const f16x8* wpO = (const f16x8*)wbO + (size_t)w * 64 + lane;

  // x/dt: thread covers 16 cols of one row (four f32x4, nontemporal)
  const int xrow = tid >> 3;          // 0..63
  const int xcol = (tid & 7) * 16;    // 0..112
  const float* xbase = x + ((size_t)(r0 + xrow) * SN) * IN_ + xcol;
  f32x4 xr0 = __builtin_nontemporal_load((const f32x4*)(xbase + (size_t)tb * IN_));
  f32x4 xr1 = __builtin_nontemporal_load((const f32x4*)(xbase + (size_t)tb * IN_ + 4));
  f32x4 xr2 = __builtin_nontemporal_load((const f32x4*)(xbase + (size_t)tb * IN_ + 8));
  f32x4 xr3 = __builtin_nontemporal_load((const f32x4*)(xbase + (size_t)tb * IN_ + 12));
  float dtr = (tid < RR) ? __builtin_nontemporal_load(dtp + (size_t)(r0 + tid) * SN + tb) : 0.f;

  int rp = 0, dp = 0;
  for (int t = tb; t < te; ++t) {
    const int wpb = rp ^ 1;

    // ---- stage x(t)/dt(t) from regs, sync, prefetch x(t+1) ----
    { f16x8 xv0 = { (f16)xr0[0], (f16)xr0[1], (f16)xr0[2], (f16)xr0[3],
                    (f16)xr1[0], (f16)xr1[1], (f16)xr1[2], (f16)xr1[3] };
      f16x8 xv1 = { (f16)xr2[0], (f16)xr2[1], (f16)xr2[2], (f16)xr2[3],
                    (f16)xr3[0], (f16)xr3[1], (f16)xr3[2], (f16)xr3[3] };
      *(f16x8*)&xA[xrow][xcol] = xv0;
      *(f16x8*)&xA[xrow][xcol + 8] = xv1; }
    if (tid < RR) dts[dp][tid] = dtr;
    __syncthreads();                                   // B0
    if (t + 1 < te) {
      xr0 = __builtin_nontemporal_load((const f32x4*)(xbase + (size_t)(t + 1) * IN_));
      xr1 = __builtin_nontemporal_load((const f32x4*)(xbase + (size_t)(t + 1) * IN_ + 4));
      xr2 = __builtin_nontemporal_load((const f32x4*)(xbase + (size_t)(t + 1) * IN_ + 8));
      xr3 = __builtin_nontemporal_load((const f32x4*)(xbase + (size_t)(t + 1) * IN_ + 12));
      if (tid < RR) dtr = __builtin_nontemporal_load(dtp + (size_t)(r0 + tid) * SN + (t + 1));
    }

    // ---- phase A: layer 0 gates [64 x 1024] = [x(t) | h0_old] @ W0cat ----
    {
      f32x4 acc[4][2][4];   // [gate][s][mtile]  = 128 VGPRs
#pragma unroll
      for (int g = 0; g < 4; ++g)
#pragma unroll
        for (int s = 0; s < 2; ++s) {
          float bv = b0r[g * 2 + s];
#pragma unroll
          for (int mt = 0; mt < 4; ++mt)
            acc[g][s][mt] = (f32x4){bv, bv, bv, bv};
        }
#pragma unroll
      for (int kt = 0; kt < 12; ++kt) {
        f16x8 af[4];
#pragma unroll
        for (int mt = 0; mt < 4; ++mt) {
          if (kt < 4)
            af[mt] = *(const f16x8*)&xA[mt * 16 + mrow][kt * 32 + kgrp];
          else
            af[mt] = *(const f16x8*)&h0s[rp][mt * 16 + mrow][(kt - 4) * 32 + kgrp];
        }
#pragma unroll
        for (int g = 0; g < 4; ++g)
#pragma unroll
          for (int s = 0; s < 2; ++s) {
            f16x8 b = wp0[(size_t)(kt * 64 + g * 16 + s) * 64];
#pragma unroll
            for (int mt = 0; mt < 4; ++mt)
              acc[g][s][mt] = MFMA16(af[mt], b, acc[g][s][mt]);
          }
      }
      // elementwise in registers -> h0 new buffer
#pragma unroll
      for (int s = 0; s < 2; ++s)
#pragma unroll
        for (int mt = 0; mt < 4; ++mt)
#pragma unroll
          for (int ri = 0; ri < 4; ++ri) {
            int row = mt * 16 + rbase + ri;
            float d = dts[dp][row];
            float f1 = fast_tanh(acc[0][s][mt][ri]);
            float f2 = fast_tanh(acc[1][s][mt][ri]);
            float sg = fast_sigmoid(acc[2][s][mt][ri] * d + acc[3][s][mt][ri]);
            h0s[wpb][row][w * 32 + s * 16 + mrow] = (f16)(f1 + sg * (f2 - f1));
          }
    }
    __syncthreads();                                   // B1: new h0 visible

    // ---- phase B: layer 1 gates [64 x 1024] = [h0_new | h1_old] @ W1cat ----
    {
      f32x4 acc[4][2][4];
#pragma unroll
      for (int g = 0; g < 4; ++g)
#pragma unroll
        for (int s = 0; s < 2; ++s) {
          float bv = b1r[g * 2 + s];
#pragma unroll
          for (int mt = 0; mt < 4; ++mt)
            acc[g][s][mt] = (f32x4){bv, bv, bv, bv};
        }
#pragma unroll
      for (int kt = 0; kt < 16; ++kt) {
        f16x8 af[4];
#pragma unroll
        for (int mt = 0; mt < 4; ++mt) {
          if (kt < 8)
            af[mt] = *(const f16x8*)&h0s[wpb][mt * 16 + mrow][kt * 32 + kgrp];
          else
            af[mt] = *(const f16x8*)&h1s[rp][mt * 16 + mrow][(kt - 8) * 32 + kgrp];
        }
#pragma unroll
        for (int g = 0; g < 4; ++g)
#pragma unroll
          for (int s = 0; s < 2; ++s) {
            f16x8 b = wp1[(size_t)(kt * 64 + g * 16 + s) * 64];
#pragma unroll
            for (int mt = 0; mt < 4; ++mt)
              acc[g][s][mt] = MFMA16(af[mt], b, acc[g][s][mt]);
          }
      }
#pragma unroll
      for (int s = 0; s < 2; ++s)
#pragma unroll
        for (int mt = 0; mt < 4; ++mt)
#pragma unroll
          for (int ri = 0; ri < 4; ++ri) {
            int row = mt * 16 + rbase + ri;
            float d = dts[dp][row];
            float f1 = fast_tanh(acc[0][s][mt][ri]);
            float f2 = fast_tanh(acc[1][s][mt][ri]);
            float sg = fast_sigmoid(acc[2][s][mt][ri] * d + acc[3][s][mt][ri]);
            h1s[wpb][row][w * 32 + s * 16 + mrow] = (f16)(f1 + sg * (f2 - f1));
          }
    }
    __syncthreads();                                   // B2: new h1 visible

    // ---- phase C: y = h1 @ Wout + bout (transient wor; skipped in warmup) --
    if (t >= tw) {
      f32x4 ao[4];
#pragma unroll
      for (int mt = 0; mt < 4; ++mt) ao[mt] = (f32x4){bOr, bOr, bOr, bOr};
#pragma unroll
      for (int kt = 0; kt < 8; ++kt) {
        f16x8 wb = wpO[(size_t)(kt * 8) * 64];
#pragma unroll
        for (int mt = 0; mt < 4; ++mt) {
          f16x8 a = *(const f16x8*)&h1s[wpb][mt * 16 + mrow][kt * 32 + kgrp];
          ao[mt] = MFMA16(a, wb, ao[mt]);
        }
      }
#pragma unroll
      for (int mt = 0; mt < 4; ++mt)
#pragma unroll
        for (int ri = 0; ri < 4; ++ri) {
          int r = mt * 16 + rbase + ri;
          __builtin_nontemporal_store(ao[mt][ri],
              out + ((size_t)(r0 + r) * SN + t) * 128 + w * 16 + mrow);
        }
    }
    rp ^= 1; dp ^= 1;
    // next-iter xA/dts stores race only with phase C (disjoint LDS);
    // B0 at the top of the loop orders everything else.
  }
}

extern "C" void kernel_launch(void* const* d_in, const int* in_sizes, int n_in,
                              void* d_out, int out_size, void* d_ws, size_t ws_size,
                              hipStream_t stream) {
  PrepArgs p;
  for (int i = 0; i < 8; ++i) {
    p.W[i] = (const float*)d_in[2 + 2 * i];
    p.b[i] = (const float*)d_in[3 + 2 * i];
  }
  p.Wout = (const float*)d_in[18];
  p.bout = (const float*)d_in[19];
  const float* x  = (const float*)d_in[0];
  const float* dt = (const float*)d_in[1];

  f16* wbase = (f16*)d_ws;
  float* bbase = (float*)((char*)d_ws + BIAS_OFF_B);

  const int prep_threads = (12 * 64 + 16 * 64 + 8 * 8) * 64 + 2176;
  int prep_blocks = (prep_threads + 255) / 256;
  prep_kernel<<<prep_blocks, 256, 0, stream>>>(p, wbase, bbase);

  const f16* wb0 = wbase;
  const f16* wb1 = wbase + WB0_SZ;
  const f16* wbO = wbase + WB0_SZ + WB1_SZ;

  scan_kernel<<<256, 512, 0, stream>>>(x, dt, wb0, wb1, wbO,
                                       (const float*)bbase, (float*)d_out);
}